// Round 1
// baseline (625.525 us; speedup 1.0000x reference)
//
#include <hip/hip_runtime.h>

// Problem constants (fixed by reference): B=2, T=32, H=64, W=64, C=64, KT=5, K=7
// All circular dims are powers of 2 -> wrap via & masks.

#define PLANE (64 * 64 * 64)          // H*W*C elements per (b,t) plane
#define ROWS  262144                  // B*T*H*W
#define NELEM 16777216                // B*T*H*W*C

// ---------------- fused dual projection GEMM ----------------
// pg[r,d] = sum_c x[r,c]*wg[c,d] + bg[d];  ph likewise.
__global__ __launch_bounds__(256) void proj2_kernel(
    const float* __restrict__ x,
    const float* __restrict__ wg, const float* __restrict__ bg,
    const float* __restrict__ wh, const float* __restrict__ bh,
    float* __restrict__ pg, float* __restrict__ ph)
{
    __shared__ float sWg[4096];
    __shared__ float sWh[4096];
    for (int i = threadIdx.x; i < 4096; i += 256) { sWg[i] = wg[i]; sWh[i] = wh[i]; }
    __syncthreads();
    const int d    = threadIdx.x & 63;
    const int wave = threadIdx.x >> 6;                 // 4 waves / block
    const long long rowBase = (long long)blockIdx.x * 64 + wave * 16;
    const float bgd = bg[d], bhd = bh[d];
    for (int rg = 0; rg < 16; rg += 4) {
        const float* x0 = x + (rowBase + rg) * 64;
        float ag0 = bgd, ag1 = bgd, ag2 = bgd, ag3 = bgd;
        float ah0 = bhd, ah1 = bhd, ah2 = bhd, ah3 = bhd;
        #pragma unroll 8
        for (int c = 0; c < 64; ++c) {
            const float wgv = sWg[c * 64 + d];
            const float whv = sWh[c * 64 + d];
            const float x0v = x0[c];
            const float x1v = x0[64 + c];
            const float x2v = x0[128 + c];
            const float x3v = x0[192 + c];
            ag0 = fmaf(x0v, wgv, ag0); ah0 = fmaf(x0v, whv, ah0);
            ag1 = fmaf(x1v, wgv, ag1); ah1 = fmaf(x1v, whv, ah1);
            ag2 = fmaf(x2v, wgv, ag2); ah2 = fmaf(x2v, whv, ah2);
            ag3 = fmaf(x3v, wgv, ag3); ah3 = fmaf(x3v, whv, ah3);
        }
        float* og = pg + (rowBase + rg) * 64 + d;
        float* oh = ph + (rowBase + rg) * 64 + d;
        og[0] = ag0; og[64] = ag1; og[128] = ag2; og[192] = ag3;
        oh[0] = ah0; oh[64] = ah1; oh[128] = ah2; oh[192] = ah3;
    }
}

// ---------------- depthwise circular 3D conv ----------------
// out[b,t,h,w,c] = sum_{kt,kh,kw} kern[c,kt,kh,kw] * in[b,(t-kt+2)&31,(h-kh+3)&63,(w-kw+3)&63,c]
#define SROW 368   // LDS input row stride in dwords (22*16=352, +16 pad -> 2-way only)
__global__ __launch_bounds__(256) void conv3d_kernel(
    const float* __restrict__ in, const float* __restrict__ kern, float* __restrict__ out)
{
    __shared__ float sIn[22 * SROW];        // 32384 B
    __shared__ float sK[5 * 7 * 7 * 16];    // 15680 B

    int bid = blockIdx.x;
    const int cg = bid & 3;  bid >>= 2;
    const int wb = bid & 3;  bid >>= 2;
    const int hb = bid & 3;  bid >>= 2;
    const int t  = bid & 31; bid >>= 5;
    const int b  = bid;
    const int h0 = hb * 16, w0 = wb * 16, c0 = cg * 16;

    // stage kernel slice: sK[tap*16 + cl] = kern[(c0+cl)*245 + tap]
    for (int i = threadIdx.x; i < 3920; i += 256) {
        const int clk = i & 15;
        const int tap = i >> 4;
        sK[tap * 16 + clk] = kern[(c0 + clk) * 245 + tap];
    }

    const int cl = threadIdx.x & 15;
    const int ih = threadIdx.x >> 4;    // 0..15
    float acc[16];
    #pragma unroll
    for (int j = 0; j < 16; ++j) acc[j] = 0.f;

    const float* base = in + (long long)b * 32 * PLANE;

    for (int kt = 0; kt < 5; ++kt) {
        const int tin = (t - kt + 2) & 31;
        const float* plane = base + (long long)tin * PLANE;
        __syncthreads();
        // stage 22x22 spatial x 16ch input tile (as float4 chunks)
        for (int idx = threadIdx.x; idx < 1936; idx += 256) {
            const int f4  = idx & 3;
            const int pos = idx >> 2;          // 0..483
            const int ii  = pos / 22;
            const int jj  = pos - ii * 22;
            const int gh  = (h0 - 3 + ii) & 63;
            const int gw  = (w0 - 3 + jj) & 63;
            const float4 v = *reinterpret_cast<const float4*>(
                plane + ((gh * 64 + gw) * 64 + c0 + f4 * 4));
            *reinterpret_cast<float4*>(&sIn[ii * SROW + jj * 16 + f4 * 4]) = v;
        }
        __syncthreads();
        #pragma unroll
        for (int kh = 0; kh < 7; ++kh) {
            const int ii = ih + 6 - kh;
            float row[22];
            #pragma unroll
            for (int jj = 0; jj < 22; ++jj) row[jj] = sIn[ii * SROW + jj * 16 + cl];
            #pragma unroll
            for (int kw = 0; kw < 7; ++kw) {
                const float kv = sK[((kt * 7 + kh) * 7 + kw) * 16 + cl];
                #pragma unroll
                for (int j = 0; j < 16; ++j)
                    acc[j] = fmaf(kv, row[j + 6 - kw], acc[j]);
            }
        }
    }
    float* op = out + (long long)b * 32 * PLANE + (long long)t * PLANE
              + ((h0 + ih) * 64 + w0) * 64 + c0 + cl;
    #pragma unroll
    for (int j = 0; j < 16; ++j) op[j * 64] = acc[j];
}

// ---------------- minGRU scan over T (linear space, all-positive) ----------------
// h_t = sigmoid(-g_t)*h_{t-1} + sigmoid(g_t)*(hid_t^2 + 1e-6), h_{-1}=0
__global__ __launch_bounds__(256) void scan_kernel(
    const float* __restrict__ gs, const float* __restrict__ hs, float* __restrict__ hout)
{
    const int tid = blockIdx.x * 256 + threadIdx.x;    // 0..524287
    const int b = tid >> 18;                           // / 262144
    const int q = tid & 262143;
    const long long bb = (long long)b * 32 * 262144 + q;
    float h = 0.f;
    for (int t = 0; t < 32; ++t) {
        const long long a = bb + (long long)t * 262144;
        const float g  = gs[a];
        const float hv = hs[a];
        const float z  = 1.f / (1.f + __expf(-g));     // sigmoid(g)
        const float f  = 1.f - z;                      // sigmoid(-g)
        const float v  = z * fmaf(hv, hv, 1e-6f);
        h = fmaf(f, h, v);
        hout[a] = h;
    }
}

// ---------------- output GEMM ----------------
__global__ __launch_bounds__(256) void outgemm_kernel(
    const float* __restrict__ hin, const float* __restrict__ w,
    const float* __restrict__ bias, float* __restrict__ out)
{
    __shared__ float sW[4096];
    for (int i = threadIdx.x; i < 4096; i += 256) sW[i] = w[i];
    __syncthreads();
    const int d    = threadIdx.x & 63;
    const int wave = threadIdx.x >> 6;
    const long long rowBase = (long long)blockIdx.x * 64 + wave * 16;
    const float bd = bias[d];
    for (int rg = 0; rg < 16; rg += 4) {
        const float* h0p = hin + (rowBase + rg) * 64;
        float a0 = bd, a1 = bd, a2 = bd, a3 = bd;
        #pragma unroll 8
        for (int c = 0; c < 64; ++c) {
            const float wv = sW[c * 64 + d];
            a0 = fmaf(h0p[c],       wv, a0);
            a1 = fmaf(h0p[64 + c],  wv, a1);
            a2 = fmaf(h0p[128 + c], wv, a2);
            a3 = fmaf(h0p[192 + c], wv, a3);
        }
        float* o = out + (rowBase + rg) * 64 + d;
        o[0] = a0; o[64] = a1; o[128] = a2; o[192] = a3;
    }
}

extern "C" void kernel_launch(void* const* d_in, const int* in_sizes, int n_in,
                              void* d_out, int out_size, void* d_ws, size_t ws_size,
                              hipStream_t stream)
{
    const float* x  = (const float*)d_in[0];
    const float* gw = (const float*)d_in[1];
    const float* gb = (const float*)d_in[2];
    const float* hw = (const float*)d_in[3];
    const float* hb = (const float*)d_in[4];
    const float* gk = (const float*)d_in[5];
    const float* hk = (const float*)d_in[6];
    const float* ow = (const float*)d_in[7];
    const float* ob = (const float*)d_in[8];

    float* D = (float*)d_out;               // also used as gate_spatial scratch
    float* A = (float*)d_ws;                // buffer A: 67 MB
    float* Bf = A + NELEM;                  // buffer B: 67 MB  (needs 134 MB ws)

    // 1) dual projection: x -> A (gate_proj), B (hidden_proj)
    proj2_kernel<<<ROWS / 64, 256, 0, stream>>>(x, gw, gb, hw, hb, A, Bf);
    // 2) gate conv: A -> D (gate_spatial lives in d_out scratch)
    conv3d_kernel<<<4096, 256, 0, stream>>>(A, gk, D);
    // 3) hidden conv: B -> A (hidden_spatial)
    conv3d_kernel<<<4096, 256, 0, stream>>>(Bf, hk, A);
    // 4) scan: (D, A) -> B (h)
    scan_kernel<<<2048, 256, 0, stream>>>(D, A, Bf);
    // 5) output GEMM: B -> D (final out, overwrites scratch)
    outgemm_kernel<<<ROWS / 64, 256, 0, stream>>>(Bf, ow, ob, D);
}

// Round 2
// 559.300 us; speedup vs baseline: 1.1184x; 1.1184x over previous
//
#include <hip/hip_runtime.h>
#include <hip/hip_fp16.h>

// Problem constants (fixed by reference): B=2, T=32, H=64, W=64, C=64, KT=5, K=7
// All circular dims are powers of 2 -> wrap via & masks.

#define PLANE (64 * 64 * 64)          // H*W*C elements per (b,t) plane
#define ROWS  262144                  // B*T*H*W
#define NELEM 16777216                // B*T*H*W*C

// ---------------- fused dual projection GEMM ----------------
__global__ __launch_bounds__(256) void proj2_kernel(
    const float* __restrict__ x,
    const float* __restrict__ wg, const float* __restrict__ bg,
    const float* __restrict__ wh, const float* __restrict__ bh,
    float* __restrict__ pg, float* __restrict__ ph)
{
    __shared__ float sWg[4096];
    __shared__ float sWh[4096];
    for (int i = threadIdx.x; i < 4096; i += 256) { sWg[i] = wg[i]; sWh[i] = wh[i]; }
    __syncthreads();
    const int d    = threadIdx.x & 63;
    const int wave = threadIdx.x >> 6;                 // 4 waves / block
    const long long rowBase = (long long)blockIdx.x * 64 + wave * 16;
    const float bgd = bg[d], bhd = bh[d];
    for (int rg = 0; rg < 16; rg += 4) {
        const float* x0 = x + (rowBase + rg) * 64;
        float ag0 = bgd, ag1 = bgd, ag2 = bgd, ag3 = bgd;
        float ah0 = bhd, ah1 = bhd, ah2 = bhd, ah3 = bhd;
        #pragma unroll 8
        for (int c = 0; c < 64; ++c) {
            const float wgv = sWg[c * 64 + d];
            const float whv = sWh[c * 64 + d];
            const float x0v = x0[c];
            const float x1v = x0[64 + c];
            const float x2v = x0[128 + c];
            const float x3v = x0[192 + c];
            ag0 = fmaf(x0v, wgv, ag0); ah0 = fmaf(x0v, whv, ah0);
            ag1 = fmaf(x1v, wgv, ag1); ah1 = fmaf(x1v, whv, ah1);
            ag2 = fmaf(x2v, wgv, ag2); ah2 = fmaf(x2v, whv, ah2);
            ag3 = fmaf(x3v, wgv, ag3); ah3 = fmaf(x3v, whv, ah3);
        }
        float* og = pg + (rowBase + rg) * 64 + d;
        float* oh = ph + (rowBase + rg) * 64 + d;
        og[0] = ag0; og[64] = ag1; og[128] = ag2; og[192] = ag3;
        oh[0] = ah0; oh[64] = ah1; oh[128] = ah2; oh[192] = ah3;
    }
}

// ---------------- depthwise circular 3D conv, packed fp16 ----------------
// out[b,t,h,w,c] = sum_{kt,kh,kw} kern[c,kt,kh,kw] * in[b,(t-kt+2)&31,(h-kh+3)&63,(w-kw+3)&63,c]
// Block: 16x16 spatial x 32 channels (16 half2 pairs). Threads: p=tid&15 (pair), ih=tid>>4.
// LDS layouts (dword units):
//   sIn[p][ii][jj]: pair-stride CS=532, row-stride RS=24 (22 rows x 22 cols used)
//     8 consecutive lanes (p=0..7): bank starts 20p mod 32 = {0,20,8,28,16,4,24,12} distinct -> conflict-free b128
//   sK[p][(kt*7+kh)*8 + kw]: pair-stride KS=284 -> starts 28p mod 32 distinct
#define CS 532
#define RS 24
#define KS 284
__global__ __launch_bounds__(256) void conv3d_kernel(
    const float* __restrict__ in, const float* __restrict__ kern, float* __restrict__ out)
{
    __shared__ __align__(16) __half2 sIn[16 * CS];   // 34048 B
    __shared__ __align__(16) __half2 sK[16 * KS];    // 18176 B

    int bid = blockIdx.x;
    const int cg = bid & 1;  bid >>= 1;
    const int wb = bid & 3;  bid >>= 2;
    const int hb = bid & 3;  bid >>= 2;
    const int t  = bid & 31; bid >>= 5;
    const int b  = bid;
    const int h0 = hb * 16, w0 = wb * 16, c0 = cg * 32;

    // stage kernel taps as half2 channel pairs
    for (int i = threadIdx.x; i < 3920; i += 256) {
        const int p   = i / 245;
        const int tap = i - p * 245;
        const int kt  = tap / 49;
        const int r2  = tap - kt * 49;
        const int kh  = r2 / 7;
        const int kw  = r2 - kh * 7;
        const float a = kern[(c0 + 2 * p) * 245 + tap];
        const float c = kern[(c0 + 2 * p + 1) * 245 + tap];
        sK[p * KS + (kt * 7 + kh) * 8 + kw] = __halves2half2(__float2half(a), __float2half(c));
    }

    const int p  = threadIdx.x & 15;
    const int ih = threadIdx.x >> 4;    // 0..15
    float accLo[16], accHi[16];
    #pragma unroll
    for (int j = 0; j < 16; ++j) { accLo[j] = 0.f; accHi[j] = 0.f; }

    const float* base = in + (long long)b * 32 * PLANE;
    const __half2 hz = __float2half2_rn(0.0f);

    for (int kt = 0; kt < 5; ++kt) {
        const int tin = (t - kt + 2) & 31;
        const float* plane = base + (long long)tin * PLANE;
        __syncthreads();
        // stage 22x22 spatial x 32ch tile: f32 -> half2 pairs
        for (int idx = threadIdx.x; idx < 3872; idx += 256) {
            const int f4  = idx & 7;           // which float4 chunk of 32 ch
            const int pos = idx >> 3;          // 0..483
            const int ii  = pos / 22;
            const int jj  = pos - ii * 22;
            const int gh  = (h0 - 3 + ii) & 63;
            const int gw  = (w0 - 3 + jj) & 63;
            const float4 v = *reinterpret_cast<const float4*>(
                plane + ((gh * 64 + gw) * 64 + c0 + f4 * 4));
            const __half2 lo = __halves2half2(__float2half(v.x), __float2half(v.y));
            const __half2 hi = __halves2half2(__float2half(v.z), __float2half(v.w));
            const int a0 = (f4 * 2) * CS + ii * RS + jj;
            sIn[a0] = lo; sIn[a0 + CS] = hi;
        }
        __syncthreads();

        __half2 h2acc[16];
        #pragma unroll
        for (int j = 0; j < 16; ++j) h2acc[j] = hz;

        #pragma unroll
        for (int kh = 0; kh < 7; ++kh) {
            const int ii = ih + 6 - kh;
            // row: 22 half2 (24 loaded) via 6 ds_read_b128
            __half2 rw[24];
            {
                int4* rv = reinterpret_cast<int4*>(rw);
                const int4* sp = reinterpret_cast<const int4*>(&sIn[p * CS + ii * RS]);
                #pragma unroll
                for (int q = 0; q < 6; ++q) rv[q] = sp[q];
            }
            // taps: 7 half2 (8 loaded) via 2 ds_read_b128
            __half2 kv[8];
            {
                int4* kvv = reinterpret_cast<int4*>(kv);
                const int4* kp = reinterpret_cast<const int4*>(&sK[p * KS + (kt * 7 + kh) * 8]);
                kvv[0] = kp[0]; kvv[1] = kp[1];
            }
            #pragma unroll
            for (int kw = 0; kw < 7; ++kw) {
                #pragma unroll
                for (int j = 0; j < 16; ++j)
                    h2acc[j] = __hfma2(kv[kw], rw[j + 6 - kw], h2acc[j]);
            }
        }
        // flush this kt-plane's f16 partials into f32 accumulators
        #pragma unroll
        for (int j = 0; j < 16; ++j) {
            const float2 lh = __half22float2(h2acc[j]);
            accLo[j] += lh.x; accHi[j] += lh.y;
        }
    }
    float* op = out + (long long)b * 32 * PLANE + (long long)t * PLANE
              + ((h0 + ih) * 64 + w0) * 64 + c0 + 2 * p;
    #pragma unroll
    for (int j = 0; j < 16; ++j)
        *reinterpret_cast<float2*>(op + j * 64) = make_float2(accLo[j], accHi[j]);
}

// ---------------- minGRU scan over T (linear space, all-positive) ----------------
__global__ __launch_bounds__(256) void scan_kernel(
    const float* __restrict__ gs, const float* __restrict__ hs, float* __restrict__ hout)
{
    const int tid = blockIdx.x * 256 + threadIdx.x;    // 0..524287
    const int b = tid >> 18;
    const int q = tid & 262143;
    const long long bb = (long long)b * 32 * 262144 + q;
    float h = 0.f;
    for (int t = 0; t < 32; ++t) {
        const long long a = bb + (long long)t * 262144;
        const float g  = gs[a];
        const float hv = hs[a];
        const float z  = 1.f / (1.f + __expf(-g));
        const float f  = 1.f - z;
        const float v  = z * fmaf(hv, hv, 1e-6f);
        h = fmaf(f, h, v);
        hout[a] = h;
    }
}

// ---------------- output GEMM ----------------
__global__ __launch_bounds__(256) void outgemm_kernel(
    const float* __restrict__ hin, const float* __restrict__ w,
    const float* __restrict__ bias, float* __restrict__ out)
{
    __shared__ float sW[4096];
    for (int i = threadIdx.x; i < 4096; i += 256) sW[i] = w[i];
    __syncthreads();
    const int d    = threadIdx.x & 63;
    const int wave = threadIdx.x >> 6;
    const long long rowBase = (long long)blockIdx.x * 64 + wave * 16;
    const float bd = bias[d];
    for (int rg = 0; rg < 16; rg += 4) {
        const float* h0p = hin + (rowBase + rg) * 64;
        float a0 = bd, a1 = bd, a2 = bd, a3 = bd;
        #pragma unroll 8
        for (int c = 0; c < 64; ++c) {
            const float wv = sW[c * 64 + d];
            a0 = fmaf(h0p[c],       wv, a0);
            a1 = fmaf(h0p[64 + c],  wv, a1);
            a2 = fmaf(h0p[128 + c], wv, a2);
            a3 = fmaf(h0p[192 + c], wv, a3);
        }
        float* o = out + (rowBase + rg) * 64 + d;
        o[0] = a0; o[64] = a1; o[128] = a2; o[192] = a3;
    }
}

extern "C" void kernel_launch(void* const* d_in, const int* in_sizes, int n_in,
                              void* d_out, int out_size, void* d_ws, size_t ws_size,
                              hipStream_t stream)
{
    const float* x  = (const float*)d_in[0];
    const float* gw = (const float*)d_in[1];
    const float* gb = (const float*)d_in[2];
    const float* hw = (const float*)d_in[3];
    const float* hb = (const float*)d_in[4];
    const float* gk = (const float*)d_in[5];
    const float* hk = (const float*)d_in[6];
    const float* ow = (const float*)d_in[7];
    const float* ob = (const float*)d_in[8];

    float* D = (float*)d_out;               // also used as gate_spatial scratch
    float* A = (float*)d_ws;                // buffer A: 67 MB
    float* Bf = A + NELEM;                  // buffer B: 67 MB

    proj2_kernel<<<ROWS / 64, 256, 0, stream>>>(x, gw, gb, hw, hb, A, Bf);
    conv3d_kernel<<<2048, 256, 0, stream>>>(A, gk, D);
    conv3d_kernel<<<2048, 256, 0, stream>>>(Bf, hk, A);
    scan_kernel<<<2048, 256, 0, stream>>>(D, A, Bf);
    outgemm_kernel<<<ROWS / 64, 256, 0, stream>>>(Bf, ow, ob, D);
}

// Round 3
// 265.595 us; speedup vs baseline: 2.3552x; 2.1058x over previous
//
#include <hip/hip_runtime.h>
#include <hip/hip_fp16.h>

// Problem constants: B=2, T=32, H=64, W=64, C=64, KT=5, K=7. Circular dims pow2 -> & masks.
#define PLANE (64 * 64 * 64)          // H*W*C elements per (b,t)
#define NELEM 16777216                // B*T*H*W*C

typedef _Float16 f16x8 __attribute__((ext_vector_type(8)));
typedef float f32x4 __attribute__((ext_vector_type(4)));

static __device__ __forceinline__ __half2 u32_as_h2(unsigned u) {
    union { unsigned u; __half2 h; } c; c.u = u; return c.h;
}

// ---------------- fused dual projection GEMM (MFMA f16) ----------------
// pg[r,d] = sum_c x[r,c]*wg[c,d] + bg[d]; ph likewise. 128 rows/block, f16 out.
__global__ __launch_bounds__(256) void proj2_kernel(
    const float* __restrict__ x,
    const float* __restrict__ wg, const float* __restrict__ bg,
    const float* __restrict__ wh, const float* __restrict__ bh,
    _Float16* __restrict__ pg, _Float16* __restrict__ ph)
{
    __shared__ __align__(16) _Float16 sX[128 * 64];     // rows, 16B-chunk XOR swizzle
    __shared__ __align__(16) _Float16 sWT[2][64 * 64];  // [mat][d][c] transposed, swizzled
    const int tid = threadIdx.x;
    const long long row0 = (long long)blockIdx.x * 128;

    #pragma unroll
    for (int kci = 0; kci < 4; ++kci) {
        const int chunk = tid + kci * 256;
        const int r = chunk >> 3, q = chunk & 7;
        const float* gp = x + (row0 + r) * 64 + q * 8;
        const float4 v0 = *reinterpret_cast<const float4*>(gp);
        const float4 v1 = *reinterpret_cast<const float4*>(gp + 4);
        f16x8 hv;
        hv[0] = (_Float16)v0.x; hv[1] = (_Float16)v0.y; hv[2] = (_Float16)v0.z; hv[3] = (_Float16)v0.w;
        hv[4] = (_Float16)v1.x; hv[5] = (_Float16)v1.y; hv[6] = (_Float16)v1.z; hv[7] = (_Float16)v1.w;
        *reinterpret_cast<f16x8*>(&sX[r * 64 + ((q ^ (r & 7)) * 8)]) = hv;
    }
    {
        const int d = tid & 63;
        const int cb = (tid >> 6) * 16;
        #pragma unroll
        for (int i = 0; i < 16; ++i) {
            const int c = cb + i;
            const int off = d * 64 + (((c >> 3) ^ (d & 7)) * 8) + (c & 7);
            sWT[0][off] = (_Float16)wg[c * 64 + d];
            sWT[1][off] = (_Float16)wh[c * 64 + d];
        }
    }
    __syncthreads();

    const int wv = tid >> 6, lm = tid & 15, lg = (tid & 63) >> 4;
    f16x8 bf[2][4][2];                       // [mat][ntile][kstep]
    #pragma unroll
    for (int nt = 0; nt < 4; ++nt) {
        const int d = nt * 16 + lm;
        #pragma unroll
        for (int s = 0; s < 2; ++s) {
            const int off = d * 64 + (((s * 4 + lg) ^ (d & 7)) * 8);
            bf[0][nt][s] = *reinterpret_cast<const f16x8*>(&sWT[0][off]);
            bf[1][nt][s] = *reinterpret_cast<const f16x8*>(&sWT[1][off]);
        }
    }
    f32x4 acc[2][2][4];                      // [mat][mtile][ntile]
    #pragma unroll
    for (int m = 0; m < 2; ++m)
        #pragma unroll
        for (int mt = 0; mt < 2; ++mt)
            #pragma unroll
            for (int nt = 0; nt < 4; ++nt)
                acc[m][mt][nt] = (f32x4){0.f, 0.f, 0.f, 0.f};

    #pragma unroll
    for (int mt = 0; mt < 2; ++mt) {
        const int r = wv * 32 + mt * 16 + lm;
        const f16x8 a0 = *reinterpret_cast<const f16x8*>(&sX[r * 64 + ((lg ^ (r & 7)) * 8)]);
        const f16x8 a1 = *reinterpret_cast<const f16x8*>(&sX[r * 64 + (((4 + lg) ^ (r & 7)) * 8)]);
        #pragma unroll
        for (int nt = 0; nt < 4; ++nt) {
            acc[0][mt][nt] = __builtin_amdgcn_mfma_f32_16x16x32_f16(a0, bf[0][nt][0], acc[0][mt][nt], 0, 0, 0);
            acc[0][mt][nt] = __builtin_amdgcn_mfma_f32_16x16x32_f16(a1, bf[0][nt][1], acc[0][mt][nt], 0, 0, 0);
            acc[1][mt][nt] = __builtin_amdgcn_mfma_f32_16x16x32_f16(a0, bf[1][nt][0], acc[1][mt][nt], 0, 0, 0);
            acc[1][mt][nt] = __builtin_amdgcn_mfma_f32_16x16x32_f16(a1, bf[1][nt][1], acc[1][mt][nt], 0, 0, 0);
        }
    }
    #pragma unroll
    for (int nt = 0; nt < 4; ++nt) {
        const int col = nt * 16 + lm;
        const float bgv = bg[col], bhv = bh[col];
        #pragma unroll
        for (int mt = 0; mt < 2; ++mt) {
            const long long rb = row0 + wv * 32 + mt * 16 + lg * 4;
            #pragma unroll
            for (int i = 0; i < 4; ++i) {
                pg[(rb + i) * 64 + col] = (_Float16)(acc[0][mt][nt][i] + bgv);
                ph[(rb + i) * 64 + col] = (_Float16)(acc[1][mt][nt][i] + bhv);
            }
        }
    }
}

// ---------------- depthwise circular 3D conv, fp16 in/out ----------------
#define CS 532
#define RS 24
#define KS 284
__global__ __launch_bounds__(256) void conv3d_kernel(
    const __half* __restrict__ in, const float* __restrict__ kern, __half* __restrict__ out)
{
    __shared__ __align__(16) __half2 sIn[16 * CS];   // 34048 B
    __shared__ __align__(16) __half2 sK[16 * KS];    // 18176 B

    int bid = blockIdx.x;
    const int cg = bid & 1;  bid >>= 1;
    const int wb = bid & 3;  bid >>= 2;
    const int hb = bid & 3;  bid >>= 2;
    const int t  = bid & 31; bid >>= 5;
    const int b  = bid;
    const int h0 = hb * 16, w0 = wb * 16, c0 = cg * 32;

    for (int i = threadIdx.x; i < 3920; i += 256) {
        const int p   = i / 245;
        const int tap = i - p * 245;
        const int kt  = tap / 49;
        const int r2  = tap - kt * 49;
        const int kh  = r2 / 7;
        const int kw  = r2 - kh * 7;
        const float a = kern[(c0 + 2 * p) * 245 + tap];
        const float c = kern[(c0 + 2 * p + 1) * 245 + tap];
        sK[p * KS + (kt * 7 + kh) * 8 + kw] = __halves2half2(__float2half(a), __float2half(c));
    }

    const int p  = threadIdx.x & 15;
    const int ih = threadIdx.x >> 4;
    float accLo[16], accHi[16];
    #pragma unroll
    for (int j = 0; j < 16; ++j) { accLo[j] = 0.f; accHi[j] = 0.f; }

    const __half* base = in + (long long)b * 32 * PLANE;
    const __half2 hz = __float2half2_rn(0.0f);

    for (int kt = 0; kt < 5; ++kt) {
        const int tin = (t - kt + 2) & 31;
        const __half* plane = base + (long long)tin * PLANE;
        __syncthreads();
        // stage 22x22 x 32ch fp16 tile: uint4 = 8 halves per chunk, 4 chunks/pos
        for (int idx = threadIdx.x; idx < 1936; idx += 256) {
            const int f4  = idx & 3;
            const int pos = idx >> 2;          // 0..483
            const int ii  = pos / 22;
            const int jj  = pos - ii * 22;
            const int gh  = (h0 - 3 + ii) & 63;
            const int gw  = (w0 - 3 + jj) & 63;
            const uint4 v = *reinterpret_cast<const uint4*>(
                plane + ((gh * 64 + gw) * 64 + c0 + f4 * 8));
            const int a0 = (f4 * 4) * CS + ii * RS + jj;
            sIn[a0         ] = u32_as_h2(v.x);
            sIn[a0 +     CS] = u32_as_h2(v.y);
            sIn[a0 + 2 * CS] = u32_as_h2(v.z);
            sIn[a0 + 3 * CS] = u32_as_h2(v.w);
        }
        __syncthreads();

        __half2 h2acc[16];
        #pragma unroll
        for (int j = 0; j < 16; ++j) h2acc[j] = hz;

        #pragma unroll
        for (int kh = 0; kh < 7; ++kh) {
            const int ii = ih + 6 - kh;
            __half2 rw[24];
            {
                int4* rv = reinterpret_cast<int4*>(rw);
                const int4* sp = reinterpret_cast<const int4*>(&sIn[p * CS + ii * RS]);
                #pragma unroll
                for (int q = 0; q < 6; ++q) rv[q] = sp[q];
            }
            __half2 kv[8];
            {
                int4* kvv = reinterpret_cast<int4*>(kv);
                const int4* kp = reinterpret_cast<const int4*>(&sK[p * KS + (kt * 7 + kh) * 8]);
                kvv[0] = kp[0]; kvv[1] = kp[1];
            }
            #pragma unroll
            for (int kw = 0; kw < 7; ++kw) {
                #pragma unroll
                for (int j = 0; j < 16; ++j)
                    h2acc[j] = __hfma2(kv[kw], rw[j + 6 - kw], h2acc[j]);
            }
        }
        #pragma unroll
        for (int j = 0; j < 16; ++j) {
            const float2 lh = __half22float2(h2acc[j]);
            accLo[j] += lh.x; accHi[j] += lh.y;
        }
    }
    __half* op = out + (long long)b * 32 * PLANE + (long long)t * PLANE
               + ((h0 + ih) * 64 + w0) * 64 + c0 + 2 * p;
    #pragma unroll
    for (int j = 0; j < 16; ++j)
        *reinterpret_cast<__half2*>(op + j * 64) = __floats2half2_rn(accLo[j], accHi[j]);
}

// ---------------- minGRU scan over T (f32 math, f16 I/O) ----------------
__global__ __launch_bounds__(256) void scan_kernel(
    const __half2* __restrict__ gs, const __half2* __restrict__ hs, __half2* __restrict__ hout)
{
    const int tid = blockIdx.x * 256 + threadIdx.x;    // 0..262143 half2 lanes
    const int b = tid >> 17;
    const int q = tid & 131071;
    const long long bb = (long long)b * 32 * 131072 + q;
    float h0 = 0.f, h1 = 0.f;
    for (int t = 0; t < 32; ++t) {
        const long long a = bb + (long long)t * 131072;
        const float2 g  = __half22float2(gs[a]);
        const float2 hv = __half22float2(hs[a]);
        const float z0 = 1.f / (1.f + __expf(-g.x));
        const float z1 = 1.f / (1.f + __expf(-g.y));
        h0 = fmaf(1.f - z0, h0, z0 * fmaf(hv.x, hv.x, 1e-6f));
        h1 = fmaf(1.f - z1, h1, z1 * fmaf(hv.y, hv.y, 1e-6f));
        hout[a] = __floats2half2_rn(h0, h1);
    }
}

// ---------------- output GEMM (MFMA f16, f32 out) ----------------
__global__ __launch_bounds__(256) void outgemm_kernel(
    const _Float16* __restrict__ hin, const float* __restrict__ w,
    const float* __restrict__ bias, float* __restrict__ out)
{
    __shared__ __align__(16) _Float16 sX[128 * 64];
    __shared__ __align__(16) _Float16 sWT[64 * 64];
    const int tid = threadIdx.x;
    const long long row0 = (long long)blockIdx.x * 128;

    #pragma unroll
    for (int kci = 0; kci < 4; ++kci) {
        const int chunk = tid + kci * 256;
        const int r = chunk >> 3, q = chunk & 7;
        const f16x8 hv = *reinterpret_cast<const f16x8*>(hin + (row0 + r) * 64 + q * 8);
        *reinterpret_cast<f16x8*>(&sX[r * 64 + ((q ^ (r & 7)) * 8)]) = hv;
    }
    {
        const int d = tid & 63;
        const int cb = (tid >> 6) * 16;
        #pragma unroll
        for (int i = 0; i < 16; ++i) {
            const int c = cb + i;
            sWT[d * 64 + (((c >> 3) ^ (d & 7)) * 8) + (c & 7)] = (_Float16)w[c * 64 + d];
        }
    }
    __syncthreads();

    const int wv = tid >> 6, lm = tid & 15, lg = (tid & 63) >> 4;
    f16x8 bf[4][2];
    #pragma unroll
    for (int nt = 0; nt < 4; ++nt) {
        const int d = nt * 16 + lm;
        #pragma unroll
        for (int s = 0; s < 2; ++s)
            bf[nt][s] = *reinterpret_cast<const f16x8*>(&sWT[d * 64 + (((s * 4 + lg) ^ (d & 7)) * 8)]);
    }
    f32x4 acc[2][4];
    #pragma unroll
    for (int mt = 0; mt < 2; ++mt)
        #pragma unroll
        for (int nt = 0; nt < 4; ++nt)
            acc[mt][nt] = (f32x4){0.f, 0.f, 0.f, 0.f};

    #pragma unroll
    for (int mt = 0; mt < 2; ++mt) {
        const int r = wv * 32 + mt * 16 + lm;
        const f16x8 a0 = *reinterpret_cast<const f16x8*>(&sX[r * 64 + ((lg ^ (r & 7)) * 8)]);
        const f16x8 a1 = *reinterpret_cast<const f16x8*>(&sX[r * 64 + (((4 + lg) ^ (r & 7)) * 8)]);
        #pragma unroll
        for (int nt = 0; nt < 4; ++nt) {
            acc[mt][nt] = __builtin_amdgcn_mfma_f32_16x16x32_f16(a0, bf[nt][0], acc[mt][nt], 0, 0, 0);
            acc[mt][nt] = __builtin_amdgcn_mfma_f32_16x16x32_f16(a1, bf[nt][1], acc[mt][nt], 0, 0, 0);
        }
    }
    #pragma unroll
    for (int nt = 0; nt < 4; ++nt) {
        const int col = nt * 16 + lm;
        const float bv = bias[col];
        #pragma unroll
        for (int mt = 0; mt < 2; ++mt) {
            const long long rb = row0 + wv * 32 + mt * 16 + lg * 4;
            #pragma unroll
            for (int i = 0; i < 4; ++i)
                out[(rb + i) * 64 + col] = acc[mt][nt][i] + bv;
        }
    }
}

extern "C" void kernel_launch(void* const* d_in, const int* in_sizes, int n_in,
                              void* d_out, int out_size, void* d_ws, size_t ws_size,
                              hipStream_t stream)
{
    const float* x  = (const float*)d_in[0];
    const float* gw = (const float*)d_in[1];
    const float* gb = (const float*)d_in[2];
    const float* hw = (const float*)d_in[3];
    const float* hb = (const float*)d_in[4];
    const float* gk = (const float*)d_in[5];
    const float* hk = (const float*)d_in[6];
    const float* ow = (const float*)d_in[7];
    const float* ob = (const float*)d_in[8];

    _Float16* W1 = (_Float16*)d_ws;          // 33.5 MB each
    _Float16* W2 = W1 + NELEM;
    _Float16* W3 = W2 + NELEM;

    // 1) proj: x -> W1 (gate_proj f16), W2 (hidden_proj f16)
    proj2_kernel<<<2048, 256, 0, stream>>>(x, gw, gb, hw, hb, W1, W2);
    // 2) gate conv: W1 -> W3 (gate_spatial)
    conv3d_kernel<<<2048, 256, 0, stream>>>((const __half*)W1, gk, (__half*)W3);
    // 3) hidden conv: W2 -> W1 (hidden_spatial; W1 dead)
    conv3d_kernel<<<2048, 256, 0, stream>>>((const __half*)W2, hk, (__half*)W1);
    // 4) scan: (W3, W1) -> W2 (h, f16; W2 dead)
    scan_kernel<<<1024, 256, 0, stream>>>((const __half2*)W3, (const __half2*)W1, (__half2*)W2);
    // 5) out GEMM: W2 -> d_out (f32)
    outgemm_kernel<<<2048, 256, 0, stream>>>(W2, ow, ob, (float*)d_out);
}